// Round 2
// baseline (4743.180 us; speedup 1.0000x reference)
//
#include <hip/hip_runtime.h>
#include <hip/hip_bf16.h>
#include <hip/hip_fp16.h>

// Problem: B=64, T=1024, INPUT=256, HIDDEN=512, OUTPUT=256
//   xh = x @ W_xh + b_h
//   h_t = tanh(h_{t-1} @ W_hh + xh_t)   (serial over t)
//   out = hs @ W_hy + b_y
//
// Round 4: 2 CUs per batch row (128 WGs). Each WG owns 256 columns of W_hh
// -> per-thread W = 1KB·/2 = 32 uint4 = 128 VGPRs -> ENTIRE slice in registers,
// no per-step weight streaming (the round-3 bottleneck: 72 KiB/step from L2).
// Per step the WG pair exchanges h halves (512 B) through agent-scope
// stores + a monotonic flag. Partner = bid^8 (same XCD under bid%8 heuristic).
// Deadlock-safe: 128 WGs always co-resident (>=1 WG/CU fits, 256 CUs);
// flags zeroed by pack kernel each launch (graph-replay safe).

#define BT 65536      // B*T
#define HID 512
#define NIN 256
#define NOUT 256
#define TSTEPS 1024
#define NBATCH 64

typedef _Float16 hf2_t __attribute__((ext_vector_type(2)));

__device__ __forceinline__ float fdot2(unsigned w, unsigned h, float acc) {
#if __has_builtin(__builtin_amdgcn_fdot2)
    return __builtin_amdgcn_fdot2(__builtin_bit_cast(hf2_t, w),
                                  __builtin_bit_cast(hf2_t, h), acc, false);
#else
    __half2 wv = __builtin_bit_cast(__half2, w);
    __half2 hv = __builtin_bit_cast(__half2, h);
    float2 wf = __half22float2(wv);
    float2 hf = __half22float2(hv);
    return acc + wf.x * hf.x + wf.y * hf.y;
#endif
}

__device__ __forceinline__ float dot4(uint4 w, uint4 h, float acc) {
    acc = fdot2(w.x, h.x, acc);
    acc = fdot2(w.y, h.y, acc);
    acc = fdot2(w.z, h.z, acc);
    acc = fdot2(w.w, h.w, acc);
    return acc;
}

__device__ __forceinline__ unsigned pack2h(float a, float b) {
    unsigned lo = (unsigned)__half_as_ushort(__float2half_rn(a));
    unsigned hi = (unsigned)__half_as_ushort(__float2half_rn(b));
    return lo | (hi << 16);
}

// cross-lane add within aligned quads via DPP quad_perm (VALU pipe, no LDS)
template <int CTRL>
__device__ __forceinline__ float dpp_add(float x) {
    int y = __builtin_amdgcn_mov_dpp(__float_as_int(x), CTRL, 0xF, 0xF, true);
    return x + __int_as_float(y);
}

// tanh(x) = 1 - 2/(e^{2x}+1); e^{2x} via v_exp_f32, division via v_rcp_f32.
__device__ __forceinline__ float fast_tanh(float x) {
    float e = __builtin_amdgcn_exp2f(x * 2.8853900817779268f);   // 2*log2(e)
    return 1.0f - 2.0f * __builtin_amdgcn_rcpf(e + 1.0f);
}

// ---------- generic load/store helpers ----------
__device__ __forceinline__ float4 load4f(const float* p) {
    return *(const float4*)p;
}
__device__ __forceinline__ float4 load4f(const __half* p) {
    ushort4 u = *(const ushort4*)p;
    float4 r;
    r.x = __half2float(__ushort_as_half(u.x));
    r.y = __half2float(__ushort_as_half(u.y));
    r.z = __half2float(__ushort_as_half(u.z));
    r.w = __half2float(__ushort_as_half(u.w));
    return r;
}
__device__ __forceinline__ void store1(float* p, float v) { *p = v; }
__device__ __forceinline__ void store1(__half* p, float v) { *p = __float2half_rn(v); }

// ---------- pack W_hh (f32 [k][col]) into per-thread f16 blobs ----------
// Scan thread t of WG-half c: g=t>>3, s=t&7; owns cols 256c+4g..+3, k-range
// [64s, 64s+64). W reg uint4 i (i=0..31): col 256c+4g+(i>>3), k = 64s+8(i&7)
// + 2u + {0,1} for word u. Blob layout wblob[(c*32+i)*512 + t] for coalesced
// startup load. Also zeroes the 128 step-flags (per-launch reset).
__global__ __launch_bounds__(128)
void pack_w2_kernel(const float* __restrict__ W,
                    unsigned* __restrict__ wblob_w,
                    int* __restrict__ flags) {
    int cb = blockIdx.x;          // 0..1023 : c = cb>>9, t = cb&511
    int c = cb >> 9, t = cb & 511;
    int w = threadIdx.x;          // 0..127 : i = w>>2, u = w&3
    int i = w >> 2, u = w & 3;
    int g = t >> 3, s = t & 7;
    int cc = i >> 3, j = i & 7;
    int col = 256 * c + 4 * g + cc;
    int k = 64 * s + 8 * j + 2 * u;
    unsigned val = pack2h(W[(size_t)k * HID + col], W[(size_t)(k + 1) * HID + col]);
    wblob_w[(size_t)(((c << 5) + i) * 512 + t) * 4 + u] = val;
    if (cb == 0) flags[w] = 0;
}

// ---------- f32 tiled GEMM with bias: C[M,N] = A[M,K] @ B[K,N] + bias[N] ----------
template <typename AT, typename CT>
__global__ __launch_bounds__(256)
void gemm_bias_kernel(const AT* __restrict__ A, const float* __restrict__ B,
                      const float* __restrict__ bias, CT* __restrict__ C,
                      int M, int N, int K) {
    const int TM = 64, TN = 64, TK = 16;
    __shared__ float As[TK][TM];
    __shared__ float Bs[TK][TN + 4];

    int tid = threadIdx.x;
    int tx = tid & 15;
    int ty = tid >> 4;
    int row0 = blockIdx.x * TM;
    int col0 = blockIdx.y * TN;

    float c[4][4];
#pragma unroll
    for (int i = 0; i < 4; ++i)
#pragma unroll
        for (int j = 0; j < 4; ++j) c[i][j] = 0.f;

    for (int kk = 0; kk < K; kk += TK) {
        {
            int ar = tid >> 2;
            int ac = (tid & 3) * 4;
            float4 av = load4f(A + (size_t)(row0 + ar) * K + kk + ac);
            As[ac + 0][ar] = av.x;
            As[ac + 1][ar] = av.y;
            As[ac + 2][ar] = av.z;
            As[ac + 3][ar] = av.w;
        }
        {
            int br = tid >> 4;
            int bc = (tid & 15) * 4;
            float4 bv = *(const float4*)(B + (size_t)(kk + br) * N + col0 + bc);
            *(float4*)&Bs[br][bc] = bv;
        }
        __syncthreads();
#pragma unroll
        for (int k = 0; k < TK; ++k) {
            float4 a = *(const float4*)&As[k][ty * 4];
            float4 b = *(const float4*)&Bs[k][tx * 4];
            float av[4] = {a.x, a.y, a.z, a.w};
            float bv[4] = {b.x, b.y, b.z, b.w};
#pragma unroll
            for (int i = 0; i < 4; ++i)
#pragma unroll
                for (int j = 0; j < 4; ++j) c[i][j] += av[i] * bv[j];
        }
        __syncthreads();
    }

#pragma unroll
    for (int j = 0; j < 4; ++j) {
        float bb = bias[col0 + tx * 4 + j];
#pragma unroll
        for (int i = 0; i < 4; ++i) {
            int r = row0 + ty * 4 + i;
            int cc = col0 + tx * 4 + j;
            store1(&C[(size_t)r * N + cc], c[i][j] + bb);
        }
    }
}

// ---------- packed-f16 dot2 GEMM with bias (2 MACs/instr) ----------
template <typename AT, typename CT>
__global__ __launch_bounds__(256)
void gemm_bias_f16_kernel(const AT* __restrict__ A, const float* __restrict__ B,
                          const float* __restrict__ bias, CT* __restrict__ C,
                          int M, int N, int K) {
    const int TM = 64, TN = 64, TK = 16;
    __shared__ unsigned Asp[TK / 2][TM];
    __shared__ unsigned Bsp[TK / 2][TN + 4];

    int tid = threadIdx.x;
    int tx = tid & 15;
    int ty = tid >> 4;
    int row0 = blockIdx.x * TM;
    int col0 = blockIdx.y * TN;

    float c[4][4];
#pragma unroll
    for (int i = 0; i < 4; ++i)
#pragma unroll
        for (int j = 0; j < 4; ++j) c[i][j] = 0.f;

    for (int kk = 0; kk < K; kk += TK) {
        {
            int ar = tid >> 2;
            int ac = (tid & 3) * 4;
            float4 av = load4f(A + (size_t)(row0 + ar) * K + kk + ac);
            Asp[(ac >> 1) + 0][ar] = pack2h(av.x, av.y);
            Asp[(ac >> 1) + 1][ar] = pack2h(av.z, av.w);
        }
        {
            int k2 = tid >> 5;
            int bc = (tid & 31) * 2;
            const float* b0 = B + (size_t)(kk + 2 * k2) * N + col0 + bc;
            const float* b1 = b0 + N;
            float2 r0 = *(const float2*)b0;
            float2 r1 = *(const float2*)b1;
            Bsp[k2][bc + 0] = pack2h(r0.x, r1.x);
            Bsp[k2][bc + 1] = pack2h(r0.y, r1.y);
        }
        __syncthreads();
#pragma unroll
        for (int k2 = 0; k2 < TK / 2; ++k2) {
            uint4 ap = *(const uint4*)&Asp[k2][ty * 4];
            uint4 bp = *(const uint4*)&Bsp[k2][tx * 4];
            unsigned av[4] = {ap.x, ap.y, ap.z, ap.w};
            unsigned bv[4] = {bp.x, bp.y, bp.z, bp.w};
#pragma unroll
            for (int i = 0; i < 4; ++i)
#pragma unroll
                for (int j = 0; j < 4; ++j) c[i][j] = fdot2(av[i], bv[j], c[i][j]);
        }
        __syncthreads();
    }

#pragma unroll
    for (int j = 0; j < 4; ++j) {
        float bb = bias[col0 + tx * 4 + j];
#pragma unroll
        for (int i = 0; i < 4; ++i) {
            int r = row0 + ty * 4 + i;
            int cc = col0 + tx * 4 + j;
            store1(&C[(size_t)r * N + cc], c[i][j] + bb);
        }
    }
}

// ---------- scan: 2 WGs per batch row, full W slice in registers ----------
// hst4 padded layout: h index H -> uint4 slot (H>>6)*9 + ((H>>3)&7), elem H&7.
// Pad (+1 uint4 per 8) makes the 8 per-wave broadcast slices hit disjoint
// bank quads on ds_read_b128.
__global__ __launch_bounds__(512, 2)
void rnn_scan_pair(const __half* __restrict__ xh,
                   const uint4* __restrict__ wblob,   // [2][32][512]
                   __half* __restrict__ hs,
                   __half* __restrict__ exch,         // [64][2 parity][2 half][256]
                   int* __restrict__ flags) {         // [64][2]
    const int bid = blockIdx.x;          // 0..127
    const int xcd = bid & 7;
    const int idx = bid >> 3;            // 0..15
    const int row = (xcd << 3) | (idx >> 1);   // 0..63, partner = bid^8
    const int c   = idx & 1;             // column half: cols [256c, 256c+256)
    const int t = threadIdx.x;
    const int g = t >> 3, s = t & 7;     // col group / k-slice [64s,64s+64)

    // whole weight slice in registers: 32 uint4 = 128 VGPRs
    uint4 W[32];
#pragma unroll
    for (int i = 0; i < 32; ++i) W[i] = wblob[(c * 32 + i) * 512 + t];

    __shared__ __align__(16) uint4 hst4[2][72];   // 2304 B, double-buffered h state
    if (t < 72) hst4[0][t] = uint4{0u, 0u, 0u, 0u};
    __syncthreads();

    // value lanes: s<2 finalize col pair C0=256c+4g+2s (after full butterfly
    // reduce every lane holds all 4 column sums)
    const int p = s;                               // pair id (valid for s<2)
    const int C0 = 256 * c + 4 * g + 2 * p;        // even
    const int L0 = C0 - 256 * c;                   // 0..254 even
    const __half* xpb = xh + (size_t)row * TSTEPS * HID + C0;
    __half* hpb = hs + (size_t)row * TSTEPS * HID + C0;
    const int slotC = (C0 >> 6) * 9 + ((C0 >> 3) & 7);
    const int wordC = slotC * 4 + ((C0 & 7) >> 1);
    unsigned* exch_me = (unsigned*)exch + ((size_t)row * 4 + c) * 128 + (L0 >> 1);
    // staging params (threads t<64): copy partner 256 halves, 8 B per lane
    const int hidx_st = 256 * (1 - c) + t * 4;
    const int word_st = ((hidx_st >> 6) * 9 + ((hidx_st >> 3) & 7)) * 4 + ((hidx_st & 7) >> 1);
    const unsigned long long* exch_pt = (const unsigned long long*)
        (exch + ((size_t)row * 4 + (1 - c)) * 256) + (t >> 1 << 0) * 0 + (t);  // + par*2*256 later
    int* myflag = flags + row * 2 + c;
    int* pflag  = flags + row * 2 + (1 - c);

    for (int step = 0; step < TSTEPS; ++step) {
        const int par = step & 1;

        unsigned xu = 0;
        if (s < 2) xu = *(const unsigned*)(xpb + (size_t)step * HID);  // early issue

        if (step > 0) {
            if (t < 64) {
                while (__hip_atomic_load(pflag, __ATOMIC_ACQUIRE,
                                         __HIP_MEMORY_SCOPE_AGENT) < step) {}
                const unsigned long long* src = (const unsigned long long*)
                    (exch + ((size_t)row * 4 + (size_t)par * 2 + (1 - c)) * 256) + t;
                unsigned long long v = __hip_atomic_load(src, __ATOMIC_RELAXED,
                                                         __HIP_MEMORY_SCOPE_AGENT);
                unsigned* lw = (unsigned*)&hst4[par][0];
                lw[word_st]     = (unsigned)v;
                lw[word_st + 1] = (unsigned)(v >> 32);
            }
            __syncthreads();
        }

        // dots: h slice s = 8 uint4 broadcast reads, 32 dot4 against reg W
        const uint4* hp4 = &hst4[par][s * 9];
        uint4 hh[8];
#pragma unroll
        for (int j = 0; j < 8; ++j) hh[j] = hp4[j];
        float a0 = 0.f, a1 = 0.f, a2 = 0.f, a3 = 0.f;
#pragma unroll
        for (int j = 0; j < 8; ++j) {
            a0 = dot4(W[j],      hh[j], a0);
            a1 = dot4(W[8 + j],  hh[j], a1);
            a2 = dot4(W[16 + j], hh[j], a2);
            a3 = dot4(W[24 + j], hh[j], a3);
        }

        // full butterfly over the 8 k-slices: xor1,xor2 on DPP, xor4 via shfl
        a0 = dpp_add<0xB1>(a0); a0 = dpp_add<0x4E>(a0); a0 += __shfl_xor(a0, 4);
        a1 = dpp_add<0xB1>(a1); a1 = dpp_add<0x4E>(a1); a1 += __shfl_xor(a1, 4);
        a2 = dpp_add<0xB1>(a2); a2 = dpp_add<0x4E>(a2); a2 += __shfl_xor(a2, 4);
        a3 = dpp_add<0xB1>(a3); a3 = dpp_add<0x4E>(a3); a3 += __shfl_xor(a3, 4);

        if (s < 2) {
            float t0 = (p == 0) ? a0 : a2;
            float t1 = (p == 0) ? a1 : a3;
            float xlo = __half2float(__ushort_as_half((unsigned short)(xu & 0xffff)));
            float xhi = __half2float(__ushort_as_half((unsigned short)(xu >> 16)));
            float h0 = fast_tanh(t0 + xlo);
            float h1 = fast_tanh(t1 + xhi);
            unsigned pv = pack2h(h0, h1);
            *(unsigned*)(hpb + (size_t)step * HID) = pv;              // hs output
            ((unsigned*)&hst4[par ^ 1][0])[wordC] = pv;               // own LDS next-state
            __hip_atomic_store(exch_me + (size_t)(par ^ 1) * 256, pv, // publish (uint idx)
                               __ATOMIC_RELAXED, __HIP_MEMORY_SCOPE_AGENT);
        }
        __syncthreads();   // drains vmcnt: all lanes' publishes device-visible
        if (t == 0)
            __hip_atomic_store(myflag, step + 1, __ATOMIC_RELEASE,
                               __HIP_MEMORY_SCOPE_AGENT);
    }
}

extern "C" void kernel_launch(void* const* d_in, const int* in_sizes, int n_in,
                              void* d_out, int out_size, void* d_ws, size_t ws_size,
                              hipStream_t stream) {
    const float* x    = (const float*)d_in[0];   // [64,1024,256]
    const float* W_xh = (const float*)d_in[1];   // [256,512]
    const float* W_hh = (const float*)d_in[2];   // [512,512]
    const float* b_h  = (const float*)d_in[3];   // [512]
    const float* W_hy = (const float*)d_in[4];   // [512,256]
    const float* b_y  = (const float*)d_in[5];   // [256]
    float* out = (float*)d_out;                  // [64,1024,256]

    char* ws = (char*)d_ws;
    unsigned* wblob = (unsigned*)ws;                          // 512 KiB
    int*      flags = (int*)(ws + (512 << 10));               // 512 B
    __half*   exch  = (__half*)(ws + (512 << 10) + 4096);     // 128 KiB
    __half*   xh    = (__half*)(ws + (1 << 20));              // 64 MiB
    __half*   hs    = (__half*)(ws + (1 << 20) + (size_t)BT * HID * 2);  // 64 MiB

    // 1) pack W_hh halves -> register blobs; zero the step flags (replay-safe)
    pack_w2_kernel<<<dim3(1024), dim3(128), 0, stream>>>(W_hh, wblob, flags);

    // 2) xh = x @ W_xh + b_h   (f32 math -> f16 C; feeds the recurrence)
    gemm_bias_kernel<float, __half>
        <<<dim3(BT / 64, HID / 64), dim3(256), 0, stream>>>(x, W_xh, b_h, xh, BT, HID, NIN);

    // 3) scan: 128 WGs, 2 per batch row, lockstep h-half exchange
    rnn_scan_pair<<<dim3(2 * NBATCH), dim3(512), 0, stream>>>(
        xh, (const uint4*)wblob, hs, exch, flags);

    // 4) out = hs @ W_hy + b_y   (packed f16 dot2; error does not recurse)
    gemm_bias_f16_kernel<__half, float>
        <<<dim3(BT / 64, NOUT / 64), dim3(256), 0, stream>>>(hs, W_hy, b_y, out, BT, NOUT, HID);
}

// Round 3
// 1887.292 us; speedup vs baseline: 2.5132x; 2.5132x over previous
//
#include <hip/hip_runtime.h>
#include <hip/hip_bf16.h>
#include <hip/hip_fp16.h>

// Problem: B=64, T=1024, INPUT=256, HIDDEN=512, OUTPUT=256
//   xh = x @ W_xh + b_h
//   h_t = tanh(h_{t-1} @ W_hh + xh_t)   (serial over t)
//   out = hs @ W_hy + b_y
//
// Round 5: revert to the verified round-3 structure (64 WGs, one CU per batch
// row, zero cross-WG traffic — round-4's per-step agent-scope exchange left L2
// and put fabric latency on the serial path, 2.5x regression).
// Change: cache ALL 16 streamed weight uint4s in LDS (128 KiB dynamic shared,
// gfx950 has 160 KiB/CU) -> zero per-step L2 weight traffic. Template fallback
// GLN=7 (== round 3, 64 KiB limit) if MaxDynamicSharedMemorySize opt-in fails.

#define BT 65536      // B*T
#define HID 512
#define NIN 256
#define NOUT 256
#define TSTEPS 1024
#define NBATCH 64

typedef _Float16 hf2_t __attribute__((ext_vector_type(2)));

__device__ __forceinline__ float fdot2(unsigned w, unsigned h, float acc) {
#if __has_builtin(__builtin_amdgcn_fdot2)
    return __builtin_amdgcn_fdot2(__builtin_bit_cast(hf2_t, w),
                                  __builtin_bit_cast(hf2_t, h), acc, false);
#else
    __half2 wv = __builtin_bit_cast(__half2, w);
    __half2 hv = __builtin_bit_cast(__half2, h);
    float2 wf = __half22float2(wv);
    float2 hf = __half22float2(hv);
    return acc + wf.x * hf.x + wf.y * hf.y;
#endif
}

__device__ __forceinline__ float dot4(uint4 w, uint4 h, float acc) {
    acc = fdot2(w.x, h.x, acc);
    acc = fdot2(w.y, h.y, acc);
    acc = fdot2(w.z, h.z, acc);
    acc = fdot2(w.w, h.w, acc);
    return acc;
}

__device__ __forceinline__ unsigned pack2h(float a, float b) {
    unsigned lo = (unsigned)__half_as_ushort(__float2half_rn(a));
    unsigned hi = (unsigned)__half_as_ushort(__float2half_rn(b));
    return lo | (hi << 16);
}

// cross-lane add within aligned quads via DPP quad_perm (VALU pipe, no LDS)
template <int CTRL>
__device__ __forceinline__ float dpp_add(float x) {
    int y = __builtin_amdgcn_mov_dpp(__float_as_int(x), CTRL, 0xF, 0xF, true);
    return x + __int_as_float(y);
}

// tanh(x) = 1 - 2/(e^{2x}+1); e^{2x} via v_exp_f32, division via v_rcp_f32.
__device__ __forceinline__ float fast_tanh(float x) {
    float e = __builtin_amdgcn_exp2f(x * 2.8853900817779268f);   // 2*log2(e)
    return 1.0f - 2.0f * __builtin_amdgcn_rcpf(e + 1.0f);
}

// ---------- generic load/store helpers ----------
__device__ __forceinline__ float4 load4f(const float* p) {
    return *(const float4*)p;
}
__device__ __forceinline__ float4 load4f(const __half* p) {
    ushort4 u = *(const ushort4*)p;
    float4 r;
    r.x = __half2float(__ushort_as_half(u.x));
    r.y = __half2float(__ushort_as_half(u.y));
    r.z = __half2float(__ushort_as_half(u.z));
    r.w = __half2float(__ushort_as_half(u.w));
    return r;
}
__device__ __forceinline__ void store1(float* p, float v) { *p = v; }
__device__ __forceinline__ void store1(__half* p, float v) { *p = __float2half_rn(v); }

// ---------- pack W_hh (f32 [k][j]) into per-thread f16 blobs ----------
// Thread t of the scan kernel: q=t>>2, s=t&3, k-range [128s,128s+128),
// columns 4q..4q+3. Cols 0-2 -> reg_blob[i][t] (i=0..47 uint4, coalesced),
// col 3 -> gcol_blob[j][t] (j=0..15 uint4; scan caches GLN of them in LDS).
__global__ __launch_bounds__(256)
void pack_w_kernel(const float* __restrict__ W,
                   unsigned* __restrict__ reg_blob,
                   unsigned* __restrict__ gcol_blob) {
    int t = blockIdx.x;      // 0..511  (scan thread id)
    int w = threadIdx.x;     // 0..255  (word index)
    int q = t >> 2, s = t & 3, k0 = 128 * s;
    if (w < 192) {
        int c = w >> 6, m = w & 63;
        int col = 4 * q + c, k = k0 + 2 * m;
        unsigned val = pack2h(W[(size_t)k * HID + col], W[(size_t)(k + 1) * HID + col]);
        int i = w >> 2, u = w & 3;
        reg_blob[i * 2048 + t * 4 + u] = val;
    } else {
        int m = w - 192;                       // 0..63
        int col = 4 * q + 3, k = k0 + 2 * m;
        unsigned val = pack2h(W[(size_t)k * HID + col], W[(size_t)(k + 1) * HID + col]);
        int j = m >> 2, u = m & 3;
        gcol_blob[j * 2048 + t * 4 + u] = val;
    }
}

// ---------- f32 tiled GEMM with bias: C[M,N] = A[M,K] @ B[K,N] + bias[N] ----------
// Used only for xh = x @ W_xh + b_h (precision feeds the recurrence).
template <typename AT, typename CT>
__global__ __launch_bounds__(256)
void gemm_bias_kernel(const AT* __restrict__ A, const float* __restrict__ B,
                      const float* __restrict__ bias, CT* __restrict__ C,
                      int M, int N, int K) {
    const int TM = 64, TN = 64, TK = 16;
    __shared__ float As[TK][TM];
    __shared__ float Bs[TK][TN + 4];

    int tid = threadIdx.x;
    int tx = tid & 15;
    int ty = tid >> 4;
    int row0 = blockIdx.x * TM;
    int col0 = blockIdx.y * TN;

    float c[4][4];
#pragma unroll
    for (int i = 0; i < 4; ++i)
#pragma unroll
        for (int j = 0; j < 4; ++j) c[i][j] = 0.f;

    for (int kk = 0; kk < K; kk += TK) {
        {
            int ar = tid >> 2;
            int ac = (tid & 3) * 4;
            float4 av = load4f(A + (size_t)(row0 + ar) * K + kk + ac);
            As[ac + 0][ar] = av.x;
            As[ac + 1][ar] = av.y;
            As[ac + 2][ar] = av.z;
            As[ac + 3][ar] = av.w;
        }
        {
            int br = tid >> 4;
            int bc = (tid & 15) * 4;
            float4 bv = *(const float4*)(B + (size_t)(kk + br) * N + col0 + bc);
            *(float4*)&Bs[br][bc] = bv;
        }
        __syncthreads();
#pragma unroll
        for (int k = 0; k < TK; ++k) {
            float4 a = *(const float4*)&As[k][ty * 4];
            float4 b = *(const float4*)&Bs[k][tx * 4];
            float av[4] = {a.x, a.y, a.z, a.w};
            float bv[4] = {b.x, b.y, b.z, b.w};
#pragma unroll
            for (int i = 0; i < 4; ++i)
#pragma unroll
                for (int j = 0; j < 4; ++j) c[i][j] += av[i] * bv[j];
        }
        __syncthreads();
    }

#pragma unroll
    for (int j = 0; j < 4; ++j) {
        float bb = bias[col0 + tx * 4 + j];
#pragma unroll
        for (int i = 0; i < 4; ++i) {
            int r = row0 + ty * 4 + i;
            int cc = col0 + tx * 4 + j;
            store1(&C[(size_t)r * N + cc], c[i][j] + bb);
        }
    }
}

// ---------- packed-f16 dot2 GEMM with bias (2 MACs/instr) ----------
// Used for out = hs @ W_hy + b_y: A is already f16; error does not recurse.
template <typename AT, typename CT>
__global__ __launch_bounds__(256)
void gemm_bias_f16_kernel(const AT* __restrict__ A, const float* __restrict__ B,
                          const float* __restrict__ bias, CT* __restrict__ C,
                          int M, int N, int K) {
    const int TM = 64, TN = 64, TK = 16;
    __shared__ unsigned Asp[TK / 2][TM];
    __shared__ unsigned Bsp[TK / 2][TN + 4];

    int tid = threadIdx.x;
    int tx = tid & 15;
    int ty = tid >> 4;
    int row0 = blockIdx.x * TM;
    int col0 = blockIdx.y * TN;

    float c[4][4];
#pragma unroll
    for (int i = 0; i < 4; ++i)
#pragma unroll
        for (int j = 0; j < 4; ++j) c[i][j] = 0.f;

    for (int kk = 0; kk < K; kk += TK) {
        {
            int ar = tid >> 2;
            int ac = (tid & 3) * 4;
            float4 av = load4f(A + (size_t)(row0 + ar) * K + kk + ac);
            Asp[(ac >> 1) + 0][ar] = pack2h(av.x, av.y);
            Asp[(ac >> 1) + 1][ar] = pack2h(av.z, av.w);
        }
        {
            int k2 = tid >> 5;
            int bc = (tid & 31) * 2;
            const float* b0 = B + (size_t)(kk + 2 * k2) * N + col0 + bc;
            const float* b1 = b0 + N;
            float2 r0 = *(const float2*)b0;
            float2 r1 = *(const float2*)b1;
            Bsp[k2][bc + 0] = pack2h(r0.x, r1.x);
            Bsp[k2][bc + 1] = pack2h(r0.y, r1.y);
        }
        __syncthreads();
#pragma unroll
        for (int k2 = 0; k2 < TK / 2; ++k2) {
            uint4 ap = *(const uint4*)&Asp[k2][ty * 4];
            uint4 bp = *(const uint4*)&Bsp[k2][tx * 4];
            unsigned av[4] = {ap.x, ap.y, ap.z, ap.w};
            unsigned bv[4] = {bp.x, bp.y, bp.z, bp.w};
#pragma unroll
            for (int i = 0; i < 4; ++i)
#pragma unroll
                for (int j = 0; j < 4; ++j) c[i][j] = fdot2(av[i], bv[j], c[i][j]);
        }
        __syncthreads();
    }

#pragma unroll
    for (int j = 0; j < 4; ++j) {
        float bb = bias[col0 + tx * 4 + j];
#pragma unroll
        for (int i = 0; i < 4; ++i) {
            int r = row0 + ty * 4 + i;
            int cc = col0 + tx * 4 + j;
            store1(&C[(size_t)r * N + cc], c[i][j] + bb);
        }
    }
}

// ---------- scan: one WG (one CU) per batch row, no inter-WG traffic ----------
// GLN streamed-column uint4s cached in dynamic LDS (GLN=16 -> 128 KiB, all of
// them, zero per-step L2 weight traffic; GLN=7 -> 56 KiB fallback == round 3).
template <int GLN>
__global__ __launch_bounds__(512, 2)
void rnn_scan_single(const __half* __restrict__ xh,
                     const uint4* __restrict__ reg_blob,    // [48][512]
                     const uint4* __restrict__ gcol_blob,   // [16][512]
                     __half* __restrict__ hs) {
    // h double-buffered; 272B slice stride keeps the 4 per-wave broadcast
    // addresses on disjoint bank quads.
    __shared__ __align__(16) __half hbuf[2][4][136];
    extern __shared__ __align__(16) uint4 gl_[];   // [GLN][512]

    const int t = threadIdx.x;
    const int b = blockIdx.x;
    const int s = t & 3;

    // 192 VGPRs of weights: columns 4q+0..2, k in [128s, 128s+128)
    uint4 W[48];
#pragma unroll
    for (int i = 0; i < 48; ++i) W[i] = reg_blob[i * 512 + t];
    // cache GLN streamed uint4s per thread in LDS (coalesced, conflict-free)
#pragma unroll
    for (int j = 0; j < GLN; ++j) gl_[j * 512 + t] = gcol_blob[j * 512 + t];

    hbuf[0][t >> 7][t & 127] = __ushort_as_half((unsigned short)0);
    hbuf[1][t >> 7][t & 127] = __ushort_as_half((unsigned short)0);
    __syncthreads();

    const __half* xp = xh + (size_t)b * TSTEPS * HID + t;
    __half* hp = hs + (size_t)b * TSTEPS * HID + t;
    const uint4* gb = gcol_blob + t;

#define GETG(j) (((j) < GLN) ? gl_[(j) * 512 + t] : gb[(size_t)(j) * 512])

    int cur = 0;
    __half prev = __ushort_as_half((unsigned short)0);

    for (int step = 0; step < TSTEPS; ++step) {
        float xv = __half2float(xp[(size_t)step * HID]);   // issued early, used late
        if (step) hp[(size_t)(step - 1) * HID] = prev;     // delayed store: far from barrier

        const uint4* hv = (const uint4*)&hbuf[cur][s][0];
        float a0 = 0.f, a1 = 0.f, a2 = 0.f, a3 = 0.f;

        // streamed column (col 4q+3): LDS for j<GLN, L2 beyond, chunked with
        // register-column dots
#pragma unroll
        for (int ch = 0; ch < 4; ++ch) {
            uint4 g0 = GETG(ch * 4 + 0);
            uint4 g1 = GETG(ch * 4 + 1);
            uint4 g2 = GETG(ch * 4 + 2);
            uint4 g3 = GETG(ch * 4 + 3);
            uint4 h0 = hv[ch * 4 + 0];
            uint4 h1 = hv[ch * 4 + 1];
            uint4 h2 = hv[ch * 4 + 2];
            uint4 h3 = hv[ch * 4 + 3];
            a0 = dot4(W[ch * 4 + 0], h0, a0);
            a1 = dot4(W[16 + ch * 4 + 0], h0, a1);
            a2 = dot4(W[32 + ch * 4 + 0], h0, a2);
            a0 = dot4(W[ch * 4 + 1], h1, a0);
            a1 = dot4(W[16 + ch * 4 + 1], h1, a1);
            a2 = dot4(W[32 + ch * 4 + 1], h1, a2);
            a0 = dot4(W[ch * 4 + 2], h2, a0);
            a1 = dot4(W[16 + ch * 4 + 2], h2, a1);
            a2 = dot4(W[32 + ch * 4 + 2], h2, a2);
            a0 = dot4(W[ch * 4 + 3], h3, a0);
            a1 = dot4(W[16 + ch * 4 + 3], h3, a1);
            a2 = dot4(W[32 + ch * 4 + 3], h3, a2);
            a3 = dot4(g0, h0, a3);
            a3 = dot4(g1, h1, a3);
            a3 = dot4(g2, h2, a3);
            a3 = dot4(g3, h3, a3);
        }
#undef GETG

        // reduce across the 4 k-slices (aligned quads) on the VALU via DPP
        a0 = dpp_add<0xB1>(a0); a0 = dpp_add<0x4E>(a0);
        a1 = dpp_add<0xB1>(a1); a1 = dpp_add<0x4E>(a1);
        a2 = dpp_add<0xB1>(a2); a2 = dpp_add<0x4E>(a2);
        a3 = dpp_add<0xB1>(a3); a3 = dpp_add<0x4E>(a3);
        float tot = (s == 0) ? a0 : (s == 1) ? a1 : (s == 2) ? a2 : a3;

        float hn = fast_tanh(tot + xv);
        prev = __float2half_rn(hn);
        hbuf[cur ^ 1][t >> 7][t & 127] = prev;
        __syncthreads();
        cur ^= 1;
    }
    hp[(size_t)(TSTEPS - 1) * HID] = prev;
}

extern "C" void kernel_launch(void* const* d_in, const int* in_sizes, int n_in,
                              void* d_out, int out_size, void* d_ws, size_t ws_size,
                              hipStream_t stream) {
    const float* x    = (const float*)d_in[0];   // [64,1024,256]
    const float* W_xh = (const float*)d_in[1];   // [256,512]
    const float* W_hh = (const float*)d_in[2];   // [512,512]
    const float* b_h  = (const float*)d_in[3];   // [512]
    const float* W_hy = (const float*)d_in[4];   // [512,256]
    const float* b_y  = (const float*)d_in[5];   // [256]
    float* out = (float*)d_out;                  // [64,1024,256]

    char* ws = (char*)d_ws;
    const size_t off_gcol = 48 * 512 * 16;                  // 384 KiB
    const size_t off_xh   = (size_t)1 << 20;                // 1 MiB
    const size_t off_hs   = off_xh + (size_t)BT * HID * 2;  // +64 MiB

    unsigned* reg_blob  = (unsigned*)ws;
    unsigned* gcol_blob = (unsigned*)(ws + off_gcol);
    __half*   xh        = (__half*)(ws + off_xh);
    __half*   hs        = (__half*)(ws + off_hs);

    // 1) pack W_hh -> per-thread f16 blobs
    pack_w_kernel<<<dim3(512), dim3(256), 0, stream>>>(W_hh, reg_blob, gcol_blob);

    // 2) xh = x @ W_xh + b_h   (f32 math -> f16 C; feeds the recurrence)
    gemm_bias_kernel<float, __half>
        <<<dim3(BT / 64, HID / 64), dim3(256), 0, stream>>>(x, W_xh, b_h, xh, BT, HID, NIN);

    // 3) scan: 64 WGs, one per batch row. Try the 128 KiB-LDS variant (all 16
    //    streamed uint4s cached, gfx950 LDS = 160 KiB/CU); fall back to the
    //    verified 56 KiB variant if the >64 KiB opt-in is unsupported.
    const int GL16_BYTES = 16 * 512 * 16;       // 131072
    hipError_t e = hipFuncSetAttribute(
        reinterpret_cast<const void*>(&rnn_scan_single<16>),
        hipFuncAttributeMaxDynamicSharedMemorySize, GL16_BYTES);
    if (e == hipSuccess) {
        rnn_scan_single<16><<<dim3(NBATCH), dim3(512), GL16_BYTES, stream>>>(
            xh, (const uint4*)reg_blob, (const uint4*)gcol_blob, hs);
    } else {
        (void)hipGetLastError();                // clear non-sticky error state
        rnn_scan_single<7><<<dim3(NBATCH), dim3(512), 7 * 512 * 16, stream>>>(
            xh, (const uint4*)reg_blob, (const uint4*)gcol_blob, hs);
    }

    // 4) out = hs @ W_hy + b_y   (packed f16 dot2; error does not recurse)
    gemm_bias_f16_kernel<__half, float>
        <<<dim3(BT / 64, NOUT / 64), dim3(256), 0, stream>>>(hs, W_hy, b_y, out, BT, NOUT, HID);
}

// Round 5
// 1868.821 us; speedup vs baseline: 2.5381x; 1.0099x over previous
//
#include <hip/hip_runtime.h>
#include <hip/hip_bf16.h>
#include <hip/hip_fp16.h>

// Problem: B=64, T=1024, INPUT=256, HIDDEN=512, OUTPUT=256
//   xh = x @ W_xh + b_h
//   h_t = tanh(h_{t-1} @ W_hh + xh_t)   (serial over t)
//   out = hs @ W_hy + b_y
//
// Round 7 (= round 6 de-risked): scan is LDS-pipe-bound (round-5 fit: 32
// ds_read_b128/thread/step x ~12cy matches measured step). 8-way k-split:
// each thread owns 8 columns x 64-k-slice -> h reads halve (16 -> 8 uint4).
// 8-lane reduce fully on VALU (quad_perm xor1/xor2 + DPP row_half_mirror).
// VGPR fixes vs round 6: gl loaded 4-at-a-time (live g regs 32->16), plain
// acc[8] array with compile-time indices (no pointer-select) -> ~245 live
// VGPRs < the 256 cap for 512-thread blocks, no scratch spill.

#define BT 65536      // B*T
#define HID 512
#define NIN 256
#define NOUT 256
#define TSTEPS 1024
#define NBATCH 64

typedef _Float16 hf2_t __attribute__((ext_vector_type(2)));

__device__ __forceinline__ float fdot2(unsigned w, unsigned h, float acc) {
#if __has_builtin(__builtin_amdgcn_fdot2)
    return __builtin_amdgcn_fdot2(__builtin_bit_cast(hf2_t, w),
                                  __builtin_bit_cast(hf2_t, h), acc, false);
#else
    __half2 wv = __builtin_bit_cast(__half2, w);
    __half2 hv = __builtin_bit_cast(__half2, h);
    float2 wf = __half22float2(wv);
    float2 hf = __half22float2(hv);
    return acc + wf.x * hf.x + wf.y * hf.y;
#endif
}

__device__ __forceinline__ float dot4(uint4 w, uint4 h, float acc) {
    acc = fdot2(w.x, h.x, acc);
    acc = fdot2(w.y, h.y, acc);
    acc = fdot2(w.z, h.z, acc);
    acc = fdot2(w.w, h.w, acc);
    return acc;
}

__device__ __forceinline__ unsigned pack2h(float a, float b) {
    unsigned lo = (unsigned)__half_as_ushort(__float2half_rn(a));
    unsigned hi = (unsigned)__half_as_ushort(__float2half_rn(b));
    return lo | (hi << 16);
}

// cross-lane add via DPP (VALU pipe, no LDS).
// 0xB1 = quad_perm [1,0,3,2] (xor1), 0x4E = quad_perm [2,3,0,1] (xor2),
// 0x141 = row_half_mirror (lane -> (l&~7)|(7-(l&7))): after xor1+xor2 it
// swaps the two quad-sums within each 8-lane group = completes an 8-reduce.
template <int CTRL>
__device__ __forceinline__ float dpp_add(float x) {
    int y = __builtin_amdgcn_mov_dpp(__float_as_int(x), CTRL, 0xF, 0xF, true);
    return x + __int_as_float(y);
}
template <int CTRL>
__device__ __forceinline__ float dpp_get(float x) {
    int y = __builtin_amdgcn_mov_dpp(__float_as_int(x), CTRL, 0xF, 0xF, true);
    return __int_as_float(y);
}

// tanh(x) = 1 - 2/(e^{2x}+1); e^{2x} via v_exp_f32, division via v_rcp_f32.
__device__ __forceinline__ float fast_tanh(float x) {
    float e = __builtin_amdgcn_exp2f(x * 2.8853900817779268f);   // 2*log2(e)
    return 1.0f - 2.0f * __builtin_amdgcn_rcpf(e + 1.0f);
}

// ---------- generic load/store helpers ----------
__device__ __forceinline__ float4 load4f(const float* p) {
    return *(const float4*)p;
}
__device__ __forceinline__ float4 load4f(const __half* p) {
    ushort4 u = *(const ushort4*)p;
    float4 r;
    r.x = __half2float(__ushort_as_half(u.x));
    r.y = __half2float(__ushort_as_half(u.y));
    r.z = __half2float(__ushort_as_half(u.z));
    r.w = __half2float(__ushort_as_half(u.w));
    return r;
}
__device__ __forceinline__ void store1(float* p, float v) { *p = v; }
__device__ __forceinline__ void store1(__half* p, float v) { *p = __float2half_rn(v); }

// ---------- pack W_hh (f32 [k][col]) into per-thread f16 blobs ----------
// Scan thread t: g=t>>3, s=t&7; owns cols 8g..8g+7, k-range [64s,64s+64).
// W uint4 i = c*8+j (c=col 0..7, j=chunk 0..7): word u holds
// pack(W[64s+8j+2u][8g+c], W[64s+8j+2u+1][8g+c]).
// c<6 -> reg_blob[i][t] (48 uint4, registers); c>=6 -> gcol_blob[i-48][t]
// (16 uint4, LDS-cached in the scan).
__global__ __launch_bounds__(256)
void pack_w_kernel(const float* __restrict__ W,
                   unsigned* __restrict__ reg_blob,
                   unsigned* __restrict__ gcol_blob) {
    int t = blockIdx.x;      // 0..511  (scan thread id)
    int w = threadIdx.x;     // 0..255  (word index)
    int i = w >> 2, u = w & 3;
    int g = t >> 3, s = t & 7;
    int c = i >> 3, j = i & 7;
    int col = 8 * g + c;
    int k = 64 * s + 8 * j + 2 * u;
    unsigned val = pack2h(W[(size_t)k * HID + col], W[(size_t)(k + 1) * HID + col]);
    if (i < 48) reg_blob[(i * 512 + t) * 4 + u] = val;
    else        gcol_blob[((i - 48) * 512 + t) * 4 + u] = val;
}

// ---------- f32 tiled GEMM with bias: C[M,N] = A[M,K] @ B[K,N] + bias[N] ----------
// Used only for xh = x @ W_xh + b_h (precision feeds the recurrence).
template <typename AT, typename CT>
__global__ __launch_bounds__(256)
void gemm_bias_kernel(const AT* __restrict__ A, const float* __restrict__ B,
                      const float* __restrict__ bias, CT* __restrict__ C,
                      int M, int N, int K) {
    const int TM = 64, TN = 64, TK = 16;
    __shared__ float As[TK][TM];
    __shared__ float Bs[TK][TN + 4];

    int tid = threadIdx.x;
    int tx = tid & 15;
    int ty = tid >> 4;
    int row0 = blockIdx.x * TM;
    int col0 = blockIdx.y * TN;

    float c[4][4];
#pragma unroll
    for (int i = 0; i < 4; ++i)
#pragma unroll
        for (int j = 0; j < 4; ++j) c[i][j] = 0.f;

    for (int kk = 0; kk < K; kk += TK) {
        {
            int ar = tid >> 2;
            int ac = (tid & 3) * 4;
            float4 av = load4f(A + (size_t)(row0 + ar) * K + kk + ac);
            As[ac + 0][ar] = av.x;
            As[ac + 1][ar] = av.y;
            As[ac + 2][ar] = av.z;
            As[ac + 3][ar] = av.w;
        }
        {
            int br = tid >> 4;
            int bc = (tid & 15) * 4;
            float4 bv = *(const float4*)(B + (size_t)(kk + br) * N + col0 + bc);
            *(float4*)&Bs[br][bc] = bv;
        }
        __syncthreads();
#pragma unroll
        for (int k = 0; k < TK; ++k) {
            float4 a = *(const float4*)&As[k][ty * 4];
            float4 b = *(const float4*)&Bs[k][tx * 4];
            float av[4] = {a.x, a.y, a.z, a.w};
            float bv[4] = {b.x, b.y, b.z, b.w};
#pragma unroll
            for (int i = 0; i < 4; ++i)
#pragma unroll
                for (int j = 0; j < 4; ++j) c[i][j] += av[i] * bv[j];
        }
        __syncthreads();
    }

#pragma unroll
    for (int j = 0; j < 4; ++j) {
        float bb = bias[col0 + tx * 4 + j];
#pragma unroll
        for (int i = 0; i < 4; ++i) {
            int r = row0 + ty * 4 + i;
            int cc = col0 + tx * 4 + j;
            store1(&C[(size_t)r * N + cc], c[i][j] + bb);
        }
    }
}

// ---------- packed-f16 dot2 GEMM with bias (2 MACs/instr) ----------
// Used for out = hs @ W_hy + b_y: A is already f16; error does not recurse.
template <typename AT, typename CT>
__global__ __launch_bounds__(256)
void gemm_bias_f16_kernel(const AT* __restrict__ A, const float* __restrict__ B,
                          const float* __restrict__ bias, CT* __restrict__ C,
                          int M, int N, int K) {
    const int TM = 64, TN = 64, TK = 16;
    __shared__ unsigned Asp[TK / 2][TM];
    __shared__ unsigned Bsp[TK / 2][TN + 4];

    int tid = threadIdx.x;
    int tx = tid & 15;
    int ty = tid >> 4;
    int row0 = blockIdx.x * TM;
    int col0 = blockIdx.y * TN;

    float c[4][4];
#pragma unroll
    for (int i = 0; i < 4; ++i)
#pragma unroll
        for (int j = 0; j < 4; ++j) c[i][j] = 0.f;

    for (int kk = 0; kk < K; kk += TK) {
        {
            int ar = tid >> 2;
            int ac = (tid & 3) * 4;
            float4 av = load4f(A + (size_t)(row0 + ar) * K + kk + ac);
            Asp[(ac >> 1) + 0][ar] = pack2h(av.x, av.y);
            Asp[(ac >> 1) + 1][ar] = pack2h(av.z, av.w);
        }
        {
            int k2 = tid >> 5;
            int bc = (tid & 31) * 2;
            const float* b0 = B + (size_t)(kk + 2 * k2) * N + col0 + bc;
            const float* b1 = b0 + N;
            float2 r0 = *(const float2*)b0;
            float2 r1 = *(const float2*)b1;
            Bsp[k2][bc + 0] = pack2h(r0.x, r1.x);
            Bsp[k2][bc + 1] = pack2h(r0.y, r1.y);
        }
        __syncthreads();
#pragma unroll
        for (int k2 = 0; k2 < TK / 2; ++k2) {
            uint4 ap = *(const uint4*)&Asp[k2][ty * 4];
            uint4 bp = *(const uint4*)&Bsp[k2][tx * 4];
            unsigned av[4] = {ap.x, ap.y, ap.z, ap.w};
            unsigned bv[4] = {bp.x, bp.y, bp.z, bp.w};
#pragma unroll
            for (int i = 0; i < 4; ++i)
#pragma unroll
                for (int j = 0; j < 4; ++j) c[i][j] = fdot2(av[i], bv[j], c[i][j]);
        }
        __syncthreads();
    }

#pragma unroll
    for (int j = 0; j < 4; ++j) {
        float bb = bias[col0 + tx * 4 + j];
#pragma unroll
        for (int i = 0; i < 4; ++i) {
            int r = row0 + ty * 4 + i;
            int cc = col0 + tx * 4 + j;
            store1(&C[(size_t)r * N + cc], c[i][j] + bb);
        }
    }
}

// ---------- scan: one WG (one CU) per batch row, 8-way k-split ----------
// h state as 64 uint4 (256 h2), padded: slice s (8 uint4) at uint4 offset s*9
// -> the 8 per-wave broadcast addresses of read j land on bank quads
// 4(s+j)%32, all distinct. h2 index H at word ((H>>5)*9 + ((H>>2)&7))*4+(H&3).
template <int GLN>
__global__ __launch_bounds__(512, 2)
void rnn_scan8(const __half* __restrict__ xh,
               const uint4* __restrict__ reg_blob,    // [48][512]
               const uint4* __restrict__ gcol_blob,   // [16][512]
               __half* __restrict__ hs) {
    __shared__ __align__(16) uint4 hbuf4[2][72];      // 2304 B double-buffered h
    extern __shared__ __align__(16) uint4 gl_[];      // [GLN][512]

    const int t = threadIdx.x;
    const int b = blockIdx.x;
    const int g = t >> 3, s = t & 7;

    // 48 uint4 of weights in registers: cols 8g..8g+5, k in [64s, 64s+64)
    uint4 W[48];
#pragma unroll
    for (int i = 0; i < 48; ++i) W[i] = reg_blob[i * 512 + t];
    // cols 8g+6, 8g+7 cached in LDS (coalesced, conflict-free)
#pragma unroll
    for (int j = 0; j < GLN; ++j) gl_[j * 512 + t] = gcol_blob[j * 512 + t];

    if (t < 72) {
        hbuf4[0][t] = uint4{0u, 0u, 0u, 0u};
        hbuf4[1][t] = uint4{0u, 0u, 0u, 0u};
    }
    __syncthreads();

    const int col = 8 * g + s;
    const __half* xp = xh + (size_t)b * TSTEPS * HID + col;
    __half* hp = hs + (size_t)b * TSTEPS * HID + col;
    const uint4* gb = gcol_blob + t;

    // h2 write slot for even lanes (pair (col, col+1)):
    const int H = col >> 1;
    const int wordC = ((H >> 5) * 9 + ((H >> 2) & 7)) * 4 + (H & 3);

#define GETG(j) (((j) < GLN) ? gl_[(j) * 512 + t] : gb[(size_t)(j) * 512])

    int cur = 0;
    __half prev = __ushort_as_half((unsigned short)0);

    for (int step = 0; step < TSTEPS; ++step) {
        float xv = __half2float(xp[(size_t)step * HID]);   // issued early, used late
        if (step) hp[(size_t)(step - 1) * HID] = prev;     // delayed store

        const uint4* hv = &hbuf4[cur][s * 9];
        float acc[8];
#pragma unroll
        for (int c = 0; c < 8; ++c) acc[c] = 0.f;

        // 2 chunks of 4 k-slots; gl columns (6,7) loaded 4-at-a-time to keep
        // live VGPRs under the 256 cap (round-6 lesson: 8-at-a-time spilled)
#pragma unroll
        for (int ch = 0; ch < 2; ++ch) {
            const int j4 = ch * 4;
            uint4 h0 = hv[j4 + 0];
            uint4 h1 = hv[j4 + 1];
            uint4 h2 = hv[j4 + 2];
            uint4 h3 = hv[j4 + 3];
#pragma unroll
            for (int c = 0; c < 6; ++c) {       // compile-time c -> static idx
                acc[c] = dot4(W[c * 8 + j4 + 0], h0, acc[c]);
                acc[c] = dot4(W[c * 8 + j4 + 1], h1, acc[c]);
                acc[c] = dot4(W[c * 8 + j4 + 2], h2, acc[c]);
                acc[c] = dot4(W[c * 8 + j4 + 3], h3, acc[c]);
            }
            {
                uint4 g0 = GETG(j4 + 0), g1 = GETG(j4 + 1);
                uint4 g2 = GETG(j4 + 2), g3 = GETG(j4 + 3);
                acc[6] = dot4(g0, h0, acc[6]); acc[6] = dot4(g1, h1, acc[6]);
                acc[6] = dot4(g2, h2, acc[6]); acc[6] = dot4(g3, h3, acc[6]);
            }
            {
                uint4 g0 = GETG(8 + j4 + 0), g1 = GETG(8 + j4 + 1);
                uint4 g2 = GETG(8 + j4 + 2), g3 = GETG(8 + j4 + 3);
                acc[7] = dot4(g0, h0, acc[7]); acc[7] = dot4(g1, h1, acc[7]);
                acc[7] = dot4(g2, h2, acc[7]); acc[7] = dot4(g3, h3, acc[7]);
            }
        }
#undef GETG

        // 8-lane reduce entirely on the VALU: xor1, xor2 (quad_perm), then
        // row_half_mirror swaps the two quad-sums of each 8-lane group.
#pragma unroll
        for (int c = 0; c < 8; ++c) {
            acc[c] = dpp_add<0xB1>(acc[c]);
            acc[c] = dpp_add<0x4E>(acc[c]);
            acc[c] = dpp_add<0x141>(acc[c]);
        }

        // lane s finalizes col 8g+s (compares are loop-invariant -> hoisted)
        float tot = acc[0];
        tot = (s == 1) ? acc[1] : tot;
        tot = (s == 2) ? acc[2] : tot;
        tot = (s == 3) ? acc[3] : tot;
        tot = (s == 4) ? acc[4] : tot;
        tot = (s == 5) ? acc[5] : tot;
        tot = (s == 6) ? acc[6] : tot;
        tot = (s == 7) ? acc[7] : tot;

        float hn = fast_tanh(tot + xv);
        prev = __float2half_rn(hn);

        // pack (col, col+1) via DPP xor1; even lane writes the h2 word
        float hi = dpp_get<0xB1>(hn);
        unsigned* hwp = (unsigned*)&hbuf4[cur ^ 1][0];
        if (!(s & 1)) hwp[wordC] = pack2h(hn, hi);
        __syncthreads();
        cur ^= 1;
    }
    hp[(size_t)(TSTEPS - 1) * HID] = prev;
}

extern "C" void kernel_launch(void* const* d_in, const int* in_sizes, int n_in,
                              void* d_out, int out_size, void* d_ws, size_t ws_size,
                              hipStream_t stream) {
    const float* x    = (const float*)d_in[0];   // [64,1024,256]
    const float* W_xh = (const float*)d_in[1];   // [256,512]
    const float* W_hh = (const float*)d_in[2];   // [512,512]
    const float* b_h  = (const float*)d_in[3];   // [512]
    const float* W_hy = (const float*)d_in[4];   // [512,256]
    const float* b_y  = (const float*)d_in[5];   // [256]
    float* out = (float*)d_out;                  // [64,1024,256]

    char* ws = (char*)d_ws;
    const size_t off_gcol = 48 * 512 * 16;                  // 384 KiB
    const size_t off_xh   = (size_t)1 << 20;                // 1 MiB
    const size_t off_hs   = off_xh + (size_t)BT * HID * 2;  // +64 MiB

    unsigned* reg_blob  = (unsigned*)ws;
    unsigned* gcol_blob = (unsigned*)(ws + off_gcol);
    __half*   xh        = (__half*)(ws + off_xh);
    __half*   hs        = (__half*)(ws + off_hs);

    // 1) pack W_hh -> per-thread f16 blobs (8-way-split geometry)
    pack_w_kernel<<<dim3(512), dim3(256), 0, stream>>>(W_hh, reg_blob, gcol_blob);

    // 2) xh = x @ W_xh + b_h   (f32 math -> f16 C; feeds the recurrence)
    gemm_bias_kernel<float, __half>
        <<<dim3(BT / 64, HID / 64), dim3(256), 0, stream>>>(x, W_xh, b_h, xh, BT, HID, NIN);

    // 3) scan: 64 WGs, one per batch row; all 16 gl uint4s in 128 KiB dynamic
    //    LDS (gfx950: 160 KiB/CU), fallback GLN=7 if the opt-in fails.
    const int GL16_BYTES = 16 * 512 * 16;       // 131072
    hipError_t e = hipFuncSetAttribute(
        reinterpret_cast<const void*>(&rnn_scan8<16>),
        hipFuncAttributeMaxDynamicSharedMemorySize, GL16_BYTES);
    if (e == hipSuccess) {
        rnn_scan8<16><<<dim3(NBATCH), dim3(512), GL16_BYTES, stream>>>(
            xh, (const uint4*)reg_blob, (const uint4*)gcol_blob, hs);
    } else {
        (void)hipGetLastError();                // clear non-sticky error state
        rnn_scan8<7><<<dim3(NBATCH), dim3(512), 7 * 512 * 16, stream>>>(
            xh, (const uint4*)reg_blob, (const uint4*)gcol_blob, hs);
    }

    // 4) out = hs @ W_hy + b_y   (packed f16 dot2; error does not recurse)
    gemm_bias_f16_kernel<__half, float>
        <<<dim3(BT / 64, NOUT / 64), dim3(256), 0, stream>>>(hs, W_hy, b_y, out, BT, NOUT, HID);
}